// Round 14
// baseline (263.847 us; speedup 1.0000x reference)
//
#include <hip/hip_runtime.h>
#include <cstdint>
#include <cstddef>

constexpr int N = 50000;      // nodes
constexpr int D = 256;        // D_IN == D_OUT
constexpr int E = 400000;     // edges per relation
constexpr int R = 4;          // relations
constexpr int AROWS = 50048;  // 782 * 64, padded M
constexpr int MTILES = AROWS / 64;  // 782
constexpr int KCAT = 1280;    // GEMM K = 4 msg planes + loop plane
constexpr int NT = KCAT / 32; // 40 K-steps

// Layouts:
//   A_t  [mt][kt 0..31][pl 0..3][row 0..63][8]  tiled msg planes  102.5 MB
//   xh   [AROWS][256] row-major fp16 (gather reads 512B/row; GEMM stages
//        the loop plane from it with strided 16B/lane)             25.6 MB
//   WT_t [nt 0..1][kt 0..39][pl 0..3][row 0..127][8]               640 KB

constexpr int NBPR = 196;     // dst buckets per relation (ceil(N/256))
constexpr int NBKT = NBPR * R;        // 784
constexpr int BCAP = 2560;            // records per bucket (mean 2048, +11 sigma)
constexpr int MAXDEG = 32;            // LDS slots per node (P(Poi(8)>32) ~ 3e-12)
constexpr int ECHUNK = 4096;          // edges per partition block
constexpr int NCHUNKS = (E + ECHUNK - 1) / ECHUNK;  // 98
constexpr int MAXOVF = 4096;          // bucket-cap overflow list (never in practice)

typedef _Float16 f16x8 __attribute__((ext_vector_type(8)));
typedef float f32x4 __attribute__((ext_vector_type(4)));

__device__ __forceinline__ void load_lds16(const void* g, void* l) {
    __builtin_amdgcn_global_load_lds(
        (const __attribute__((address_space(1))) void*)g,
        (__attribute__((address_space(3))) void*)l, 16, 0, 0);
}

__device__ __forceinline__ float fast_tanh(float x) {
    const float xc = fminf(fmaxf(x, -9.0f), 9.0f);
    const float t = __builtin_amdgcn_exp2f(xc * 2.8853900817779268f);  // e^{2x}
    return (t - 1.0f) / (t + 1.0f);
}

// ---------------------------------------------------------------------------
// WT_t build: linear write (chunk order == memory order). Chunk i -> 8 fp16.
// ---------------------------------------------------------------------------
__global__ __launch_bounds__(256)
void wt_build_kernel(const float* __restrict__ w, const float* __restrict__ lw,
                     _Float16* __restrict__ wt) {
    const int i = blockIdx.x * blockDim.x + threadIdx.x;  // 16B chunk index
    if (i >= 2 * 40 * 4 * 128) return;                    // 40960
    const int nt = i / 20480;
    const int r1 = i - nt * 20480;
    const int kt = r1 >> 9;           // /512
    const int r2 = r1 & 511;
    const int pl = r2 >> 7;
    const int row = r2 & 127;
    const int kb = kt * 32 + pl * 8;
    const int col = nt * 128 + row;
    f16x8 v;
#pragma unroll
    for (int j = 0; j < 8; ++j) {
        const int k = kb + j;
        const float val = (k < 1024) ? w[((k >> 8) << 16) + ((k & 255) << 8) + col]
                                     : lw[((k - 1024) << 8) + col];
        v[j] = (_Float16)val;
    }
    *reinterpret_cast<f16x8*>(wt + (size_t)i * 8) = v;
}

// ---------------------------------------------------------------------------
// x fp32 -> row-major fp16 xh[AROWS][256]; rows >= N zeroed (clean GEMM tail).
// ---------------------------------------------------------------------------
__global__ __launch_bounds__(256)
void convert_x_kernel(const float* __restrict__ x, _Float16* __restrict__ xh) {
    const long i = (long)blockIdx.x * blockDim.x + threadIdx.x;
    if (i >= (long)AROWS * 32) return;
    const int n = (int)(i >> 5);
    const int cx = (int)(i & 31);
    f16x8 v;
    if (n < N) {
        const float4* s = reinterpret_cast<const float4*>(x + (size_t)n * D + cx * 8);
        const float4 a = s[0], b = s[1];
        v[0] = (_Float16)a.x; v[1] = (_Float16)a.y;
        v[2] = (_Float16)a.z; v[3] = (_Float16)a.w;
        v[4] = (_Float16)b.x; v[5] = (_Float16)b.y;
        v[6] = (_Float16)b.z; v[7] = (_Float16)b.w;
    } else {
#pragma unroll
        for (int j = 0; j < 8; ++j) v[j] = (_Float16)0.f;
    }
    *reinterpret_cast<f16x8*>(xh + (size_t)n * D + cx * 8) = v;
}

// ---------------------------------------------------------------------------
// Pass A: multisplit edges into 196 dst-range buckets per relation (unchanged).
// ---------------------------------------------------------------------------
__global__ __launch_bounds__(256)
void partition_kernel(const int* __restrict__ edges, int* __restrict__ gcnt,
                      uint* __restrict__ buckets, int* __restrict__ ovf_n,
                      int2* __restrict__ ovf) {
    __shared__ int hist[256], base[256], run[256], gbase[256], ps[256];
    __shared__ int tot_s;
    __shared__ uint staging[ECHUNK];
    const int t = threadIdx.x;
    const int r = blockIdx.y;
    const int* srcp = edges + (size_t)r * 2 * E;
    const int* dstp = srcp + E;
    const int e0 = blockIdx.x * ECHUNK;

    hist[t] = 0;
    run[t] = 0;
    __syncthreads();

    uint rec[16];
#pragma unroll
    for (int u = 0; u < 16; ++u) {
        const int i = e0 + u * 256 + t;
        if (i < E) {
            rec[u] = ((uint)srcp[i] << 16) | (uint)dstp[i];
            atomicAdd(&hist[(rec[u] & 0xFFFFu) >> 8], 1);
        } else {
            rec[u] = 0xFFFFFFFFu;  // invalid marker (src=65535 impossible)
        }
    }
    __syncthreads();

    const int v = hist[t];
    ps[t] = v;
    __syncthreads();
    for (int off = 1; off < 256; off <<= 1) {
        const int x = (t >= off) ? ps[t - off] : 0;
        __syncthreads();
        ps[t] += x;
        __syncthreads();
    }
    base[t] = ps[t] - v;
    if (t == 255) tot_s = ps[255];
    if (v > 0) gbase[t] = atomicAdd(&gcnt[r * NBPR + t], v);
    __syncthreads();

#pragma unroll
    for (int u = 0; u < 16; ++u) {
        if (rec[u] != 0xFFFFFFFFu) {
            const int bl = (rec[u] & 0xFFFFu) >> 8;
            const int pos = base[bl] + atomicAdd(&run[bl], 1);
            staging[pos] = rec[u];
        }
    }
    __syncthreads();

    const int total = tot_s;
    for (int j = t; j < total; j += 256) {
        const uint rc = staging[j];
        const int bl = (rc & 0xFFFFu) >> 8;
        const int gp = gbase[bl] + (j - base[bl]);
        if (gp < BCAP) {
            buckets[(size_t)(r * NBPR + bl) * BCAP + gp] = rc;
        } else {  // statistically never (11 sigma); correctness fallback
            const int o = atomicAdd(ovf_n, 1);
            if (o < MAXOVF)
                ovf[o] = make_int2(r * N + (int)(rc & 0xFFFFu), (int)(rc >> 16));
        }
    }
}

// ---------------------------------------------------------------------------
// Pass B fused with gather: one block per (bucket, quarter) = 64 dst nodes.
// Hot path: 2-NODE INTERLEAVE per wave (nodes wi, wi+8): two register accs,
// 8 independent 16B row loads in flight per trip, uniform trip count,
// exec-mask predication (no divergent breaks). Rare paths (slot overflow,
// bucket-cap overflow) evicted to a separate loop. Results staged in LDS
// msg tile then written out linearly (coalesced full lines).
// ---------------------------------------------------------------------------
__global__ __launch_bounds__(256)
void bucket_gather_kernel(const uint* __restrict__ buckets,
                          const int* __restrict__ gcnt,
                          const _Float16* __restrict__ xh,
                          const int2* __restrict__ ovf,
                          const int* __restrict__ ovf_n,
                          _Float16* __restrict__ A_t) {
    __shared__ int lcnt[64];
    __shared__ ushort lslots[64][MAXDEG];
    __shared__ _Float16 msg[64][264];   // padded: stride 528B
    const int t = threadIdx.x;
    const int b = blockIdx.x >> 2;       // bucket 0..783
    const int quarter = blockIdx.x & 3;  // 64-node quarter
    const int r = b / NBPR;
    const int bl = b - r * NBPR;
    const int d0 = (bl << 8) + (quarter << 6);
    if (d0 >= N) return;                 // whole quarter out of range
    const int mt = d0 >> 6;              // A_t m-tile (d0 is 64-aligned)

    if (t < 64) lcnt[t] = 0;
    __syncthreads();

    const int nb = min(gcnt[b], BCAP);
    const uint* brec = buckets + (size_t)b * BCAP;
    for (int j = t; j < nb; j += 256) {
        const uint rc = brec[j];
        const int wi = (int)(rc & 0xFFFFu) - d0;
        if ((unsigned)wi < 64u) {
            const int pos = atomicAdd(&lcnt[wi], 1);
            if (pos < MAXDEG) lslots[wi][pos] = (ushort)(rc >> 16);
        }
    }
    __syncthreads();

    const int lane = t & 63;
    const int wv = t >> 6;           // wave 0..3 handles 16 nodes
    const int hf = lane >> 5;        // half-wave: even/odd edges
    const int cx = lane & 31;        // 16B chunk 0..31 of the 256-col row
    const int on = min(*ovf_n, MAXOVF);
    const int nb0 = wv * 16;

    auto xrow = [&](int s) -> f16x8 {
        return *reinterpret_cast<const f16x8*>(xh + (size_t)s * D + cx * 8);
    };

    // ---- fast path: 2-node interleave, 8 loads in flight per trip
    for (int p = 0; p < 8; ++p) {
        const int wiA = nb0 + p, wiB = nb0 + 8 + p;
        const int dA = d0 + wiA, dB = d0 + wiB;
        const int mAr = (dA < N) ? lcnt[wiA] : 0;   // true in-bucket counts
        const int mBr = (dB < N) ? lcnt[wiB] : 0;
        const int mA = (mAr <= MAXDEG) ? mAr : 0;   // big nodes -> rare path
        const int mB = (mBr <= MAXDEG) ? mBr : 0;
        const int tmax = ((mA > mB ? mA : mB) + 1) >> 1;  // rows per half (max)
        const int trips = (tmax + 3) >> 2;                 // wave-uniform

        float accA[8] = {}, accB[8] = {};
        int jA = hf, jB = hf;
        for (int tr = 0; tr < trips; ++tr) {
            f16x8 va[4], vb[4];
            int sa[4], sb[4];
#pragma unroll
            for (int u = 0; u < 4; ++u) {
                const int ja = jA + 2 * u;
                const int jb = jB + 2 * u;
                sa[u] = (ja < mA) ? (int)lslots[wiA][ja] : -1;
                sb[u] = (jb < mB) ? (int)lslots[wiB][jb] : -1;
                if (sa[u] >= 0) va[u] = xrow(sa[u]);
                if (sb[u] >= 0) vb[u] = xrow(sb[u]);
            }
#pragma unroll
            for (int u = 0; u < 4; ++u) {
                if (sa[u] >= 0) {
#pragma unroll
                    for (int k = 0; k < 8; ++k) accA[k] += (float)va[u][k];
                }
                if (sb[u] >= 0) {
#pragma unroll
                    for (int k = 0; k < 8; ++k) accB[k] += (float)vb[u][k];
                }
            }
            jA += 8;
            jB += 8;
        }

        int ecA = mAr, ecB = mBr;
        if (on > 0) {  // bucket-cap overflow additions (never in practice)
            if (mAr <= MAXDEG && dA < N) {
                const int wfull = r * N + dA;
                for (int o = 0; o < on; ++o) {
                    const int2 e2 = ovf[o];
                    if (e2.x == wfull) {
                        ecA++;
                        if (hf == 0) {
                            const f16x8 vv = xrow(e2.y);
#pragma unroll
                            for (int k = 0; k < 8; ++k) accA[k] += (float)vv[k];
                        }
                    }
                }
            }
            if (mBr <= MAXDEG && dB < N) {
                const int wfull = r * N + dB;
                for (int o = 0; o < on; ++o) {
                    const int2 e2 = ovf[o];
                    if (e2.x == wfull) {
                        ecB++;
                        if (hf == 0) {
                            const f16x8 vv = xrow(e2.y);
#pragma unroll
                            for (int k = 0; k < 8; ++k) accB[k] += (float)vv[k];
                        }
                    }
                }
            }
        }

#pragma unroll
        for (int k = 0; k < 8; ++k) {
            accA[k] += __shfl_xor(accA[k], 32);
            accB[k] += __shfl_xor(accB[k], 32);
        }
        if (hf == 0) {
            if (mAr <= MAXDEG) {  // rare-path nodes written later
                const float rs = 1.0f / fmaxf((float)ecA, 1.0f);
                f16x8 o8;
#pragma unroll
                for (int k = 0; k < 8; ++k) o8[k] = (_Float16)(accA[k] * rs);
                *reinterpret_cast<f16x8*>(&msg[wiA][cx * 8]) = o8;
            }
            if (mBr <= MAXDEG) {
                const float rs = 1.0f / fmaxf((float)ecB, 1.0f);
                f16x8 o8;
#pragma unroll
                for (int k = 0; k < 8; ++k) o8[k] = (_Float16)(accB[k] * rs);
                *reinterpret_cast<f16x8*>(&msg[wiB][cx * 8]) = o8;
            }
        }
    }

    // ---- rare path: nodes with slot overflow (m > MAXDEG): full bucket scan
    for (int wi = nb0; wi < nb0 + 16; ++wi) {
        const int d = d0 + wi;
        if (d >= N) continue;
        const int m = lcnt[wi];
        if (m <= MAXDEG) continue;
        float acc[8] = {};
        for (int j = hf; j < nb; j += 2) {
            const uint rc = brec[j];
            if ((int)(rc & 0xFFFFu) == d) {
                const f16x8 vv = xrow((int)(rc >> 16));
#pragma unroll
                for (int k = 0; k < 8; ++k) acc[k] += (float)vv[k];
            }
        }
        int ecnt = m;
        if (on > 0) {
            const int wfull = r * N + d;
            for (int o = 0; o < on; ++o) {
                const int2 e2 = ovf[o];
                if (e2.x == wfull) {
                    ecnt++;
                    if (hf == 0) {
                        const f16x8 vv = xrow(e2.y);
#pragma unroll
                        for (int k = 0; k < 8; ++k) acc[k] += (float)vv[k];
                    }
                }
            }
        }
#pragma unroll
        for (int k = 0; k < 8; ++k) acc[k] += __shfl_xor(acc[k], 32);
        if (hf == 0) {
            const float rs = 1.0f / fmaxf((float)ecnt, 1.0f);
            f16x8 o8;
#pragma unroll
            for (int k = 0; k < 8; ++k) o8[k] = (_Float16)(acc[k] * rs);
            *reinterpret_cast<f16x8*>(&msg[wi][cx * 8]) = o8;
        }
    }
    __syncthreads();

    // cooperative linear write-out of the 32KB (mt, r) region of A_t.
    // chunk g (16B): row = g&63, q = g>>6 (0..31), col = (q>>2)*32 + (q&3)*8.
    _Float16* dst = A_t + ((size_t)mt * 32 + r * 8) * 2048;
#pragma unroll
    for (int i = 0; i < 8; ++i) {
        const int g = i * 256 + t;
        const int row = g & 63;
        const int q = g >> 6;
        const int c = (q >> 2) * 32 + (q & 3) * 8;
        const f16x8 v = *reinterpret_cast<const f16x8*>(&msg[row][c]);
        *reinterpret_cast<f16x8*>(dst + (size_t)g * 8) = v;
    }
}

// ---------------------------------------------------------------------------
// out[N,256] = tanh( [A_t | xh] @ WT_t^T + bias ), fp32 accum/out.
// BM=64, BN=128, BK=32, 4 waves. 3-buffer DEPTH-2 pipeline, counted vmcnt
// (3 loads/wave/stage; never 0 in main loop). kt<32: contiguous 1KB from
// tiled A_t; kt>=32: loop plane from row-major xh (8/40 steps, L3-resident).
// ---------------------------------------------------------------------------
__global__ __launch_bounds__(256)
void gemm_final_kernel(const _Float16* __restrict__ A_t,
                       const _Float16* __restrict__ xh,
                       const _Float16* __restrict__ WT_t,
                       const float* __restrict__ bias, float* __restrict__ C) {
    __shared__ _Float16 As[3][4][64][8];    // 3 x 4KB
    __shared__ _Float16 Bs[3][4][128][8];   // 3 x 8KB

    const int t = threadIdx.x;
    const int lane = t & 63;
    const int w = t >> 6;
    const int mt = blockIdx.x;           // 64-row m-tile
    const int nt = blockIdx.y;           // 128-col n-tile
    const long m0 = (long)mt * 64;

    f32x4 acc[8];
#pragma unroll
    for (int j = 0; j < 8; ++j) acc[j] = (f32x4){0.f, 0.f, 0.f, 0.f};

    const int kg = lane >> 4;
    const int rr = lane & 15;

    auto stage = [&](int kt, int buf) {
        const _Float16* asrc =
            (kt < 32)
                ? A_t + ((size_t)mt * 32 + kt) * 2048 + w * 512 + lane * 8
                : xh + (size_t)(m0 + lane) * D + (kt - 32) * 32 + w * 8;
        load_lds16(asrc, &As[buf][0][0][0] + w * 512);
        const _Float16* bsrc = WT_t + ((size_t)nt * 40 + kt) * 4096 + w * 1024 + lane * 8;
        load_lds16(bsrc, &Bs[buf][0][0][0] + w * 1024);
        load_lds16(bsrc + 512, &Bs[buf][0][0][0] + w * 1024 + 512);
    };

    auto compute = [&](int buf) {
        f16x8 af, bf[8];
        af = *reinterpret_cast<const f16x8*>(&As[buf][kg][w * 16 + rr][0]);
#pragma unroll
        for (int g = 0; g < 8; ++g)
            bf[g] = *reinterpret_cast<const f16x8*>(&Bs[buf][kg][g * 16 + rr][0]);
        __builtin_amdgcn_s_setprio(1);
#pragma unroll
        for (int j = 0; j < 8; ++j)
            acc[j] = __builtin_amdgcn_mfma_f32_16x16x32_f16(af, bf[j], acc[j], 0, 0, 0);
        __builtin_amdgcn_s_setprio(0);
    };

    // prologue: stage tiles 0,1 (6 loads in flight per wave)
    stage(0, 0);
    stage(1, 1);

    for (int kt = 0; kt < NT - 2; ++kt) {
        asm volatile("s_waitcnt vmcnt(3)" ::: "memory");  // tile kt landed
        __builtin_amdgcn_sched_barrier(0);
        __builtin_amdgcn_s_barrier();  // all waves: tile kt landed; compute(kt-1) done
        __builtin_amdgcn_sched_barrier(0);
        stage(kt + 2, (kt + 2) % 3);
        compute(kt % 3);
    }
    // kt = NT-2: only tile NT-1's 3 loads outstanding after this wait
    asm volatile("s_waitcnt vmcnt(3)" ::: "memory");
    __builtin_amdgcn_sched_barrier(0);
    __builtin_amdgcn_s_barrier();
    __builtin_amdgcn_sched_barrier(0);
    compute((NT - 2) % 3);
    // kt = NT-1
    asm volatile("s_waitcnt vmcnt(0)" ::: "memory");
    __builtin_amdgcn_sched_barrier(0);
    __builtin_amdgcn_s_barrier();
    __builtin_amdgcn_sched_barrier(0);
    compute((NT - 1) % 3);

    // epilogue: C/D map col=lane&15, row=(lane>>4)*4+reg
    const int crow0 = (lane >> 4) * 4;
    const int ccol = lane & 15;
    const long rowb = m0 + w * 16 + crow0;
#pragma unroll
    for (int j = 0; j < 8; ++j) {
        const int col = nt * 128 + j * 16 + ccol;
        const float b = bias[col];
#pragma unroll
        for (int q = 0; q < 4; ++q) {
            const long rgl = rowb + q;
            if (rgl < N) C[rgl * 256 + col] = fast_tanh(acc[j][q] + b);
        }
    }
}

// ---------------------------------------------------------------------------
extern "C" void kernel_launch(void* const* d_in, const int* in_sizes, int n_in,
                              void* d_out, int out_size, void* d_ws, size_t ws_size,
                              hipStream_t stream) {
    const float* x           = (const float*)d_in[0];
    const int*   edges       = (const int*)d_in[1];   // [4][2][400000] int32
    const float* weight      = (const float*)d_in[2]; // [4][256][256]
    const float* loop_weight = (const float*)d_in[3]; // [256][256]
    const float* h_bias      = (const float*)d_in[4]; // [256]
    float*       out         = (float*)d_out;
    (void)in_sizes; (void)n_in; (void)out_size; (void)ws_size;

    size_t off = 0;
    auto carve = [&](size_t bytes) -> void* {
        void* p = (char*)d_ws + off;
        off = (off + bytes + 255) & ~(size_t)255;
        return p;
    };

    _Float16* A_t  = (_Float16*)carve((size_t)MTILES * 32 * 2048 * sizeof(_Float16)); // 102.5 MB
    _Float16* xh   = (_Float16*)carve((size_t)AROWS * D * sizeof(_Float16));          // 25.6 MB
    _Float16* WT_t = (_Float16*)carve((size_t)2 * 40 * 4096 * sizeof(_Float16));      // 640 KB
    int*      gcnt  = (int*)carve((size_t)NBKT * sizeof(int));
    int*      ovf_n = (int*)carve(256);
    int2*     ovf   = (int2*)carve((size_t)MAXOVF * sizeof(int2));
    // ws total ~128.8 MB (proven available).
    // bucket array (8 MB) aliases d_out: dead before gemm_final overwrites it.
    uint* buckets = (uint*)d_out;  // NBKT*BCAP*4 = 8.03 MB <= 51.2 MB

    hipMemsetAsync(gcnt, 0, (size_t)NBKT * sizeof(int), stream);
    hipMemsetAsync(ovf_n, 0, sizeof(int), stream);

    wt_build_kernel<<<(40960 + 255) / 256, 256, 0, stream>>>(weight, loop_weight, WT_t);
    convert_x_kernel<<<((long)AROWS * 32 + 255) / 256, 256, 0, stream>>>(x, xh);

    // multisplit edges -> dst-range buckets
    partition_kernel<<<dim3(NCHUNKS, R), 256, 0, stream>>>(edges, gcnt, buckets,
                                                           ovf_n, ovf);
    // LDS slot build + gather fused; reads row-major xh, writes tiled A_t
    // via LDS-staged coalesced write-out
    bucket_gather_kernel<<<NBKT * 4, 256, 0, stream>>>(buckets, gcnt, xh,
                                                       ovf, ovf_n, A_t);
    // out = tanh([A_t | xh] @ WT_t + bias)
    gemm_final_kernel<<<dim3(MTILES, 2), 256, 0, stream>>>(A_t, xh, WT_t, h_bias, out);
}

// Round 15
// 235.249 us; speedup vs baseline: 1.1216x; 1.1216x over previous
//
#include <hip/hip_runtime.h>
#include <cstdint>
#include <cstddef>

constexpr int N = 50000;      // nodes
constexpr int D = 256;        // D_IN == D_OUT
constexpr int E = 400000;     // edges per relation
constexpr int R = 4;          // relations
constexpr int AROWS = 50048;  // 782 * 64, padded M
constexpr int MTILES = AROWS / 64;  // 782
constexpr int KCAT = 1280;    // GEMM K = 4 msg planes + loop plane
constexpr int NT = KCAT / 32; // 40 K-steps

// Layouts:
//   A_t  [mt][kt 0..31][pl 0..3][row 0..63][8]  tiled msg planes  102.5 MB
//   xh   [AROWS][256] row-major fp16 (gather reads 512B/row; GEMM stages
//        the loop plane from it with strided 16B/lane)             25.6 MB
//   WT_t [nt 0..1][kt 0..39][pl 0..3][row 0..127][8]               640 KB

constexpr int NBPR = 196;     // dst buckets per relation (ceil(N/256))
constexpr int NBKT = NBPR * R;        // 784
constexpr int BCAP = 2560;            // records per bucket (mean 2048, +11 sigma)
constexpr int MAXDEG = 32;            // LDS slots per node (P(Poi(8)>32) ~ 3e-12)
constexpr int ECHUNK = 4096;          // edges per partition block
constexpr int NCHUNKS = (E + ECHUNK - 1) / ECHUNK;  // 98
constexpr int MAXOVF = 4096;          // bucket-cap overflow list (never in practice)

typedef _Float16 f16x8 __attribute__((ext_vector_type(8)));
typedef float f32x4 __attribute__((ext_vector_type(4)));

__device__ __forceinline__ void load_lds16(const void* g, void* l) {
    __builtin_amdgcn_global_load_lds(
        (const __attribute__((address_space(1))) void*)g,
        (__attribute__((address_space(3))) void*)l, 16, 0, 0);
}

__device__ __forceinline__ float fast_tanh(float x) {
    const float xc = fminf(fmaxf(x, -9.0f), 9.0f);
    const float t = __builtin_amdgcn_exp2f(xc * 2.8853900817779268f);  // e^{2x}
    return (t - 1.0f) / (t + 1.0f);
}

// ---------------------------------------------------------------------------
// WT_t build: linear write (chunk order == memory order). Chunk i -> 8 fp16.
// ---------------------------------------------------------------------------
__global__ __launch_bounds__(256)
void wt_build_kernel(const float* __restrict__ w, const float* __restrict__ lw,
                     _Float16* __restrict__ wt) {
    const int i = blockIdx.x * blockDim.x + threadIdx.x;  // 16B chunk index
    if (i >= 2 * 40 * 4 * 128) return;                    // 40960
    const int nt = i / 20480;
    const int r1 = i - nt * 20480;
    const int kt = r1 >> 9;           // /512
    const int r2 = r1 & 511;
    const int pl = r2 >> 7;
    const int row = r2 & 127;
    const int kb = kt * 32 + pl * 8;
    const int col = nt * 128 + row;
    f16x8 v;
#pragma unroll
    for (int j = 0; j < 8; ++j) {
        const int k = kb + j;
        const float val = (k < 1024) ? w[((k >> 8) << 16) + ((k & 255) << 8) + col]
                                     : lw[((k - 1024) << 8) + col];
        v[j] = (_Float16)val;
    }
    *reinterpret_cast<f16x8*>(wt + (size_t)i * 8) = v;
}

// ---------------------------------------------------------------------------
// x fp32 -> row-major fp16 xh[AROWS][256]; rows >= N zeroed (clean GEMM tail).
// ---------------------------------------------------------------------------
__global__ __launch_bounds__(256)
void convert_x_kernel(const float* __restrict__ x, _Float16* __restrict__ xh) {
    const long i = (long)blockIdx.x * blockDim.x + threadIdx.x;
    if (i >= (long)AROWS * 32) return;
    const int n = (int)(i >> 5);
    const int cx = (int)(i & 31);
    f16x8 v;
    if (n < N) {
        const float4* s = reinterpret_cast<const float4*>(x + (size_t)n * D + cx * 8);
        const float4 a = s[0], b = s[1];
        v[0] = (_Float16)a.x; v[1] = (_Float16)a.y;
        v[2] = (_Float16)a.z; v[3] = (_Float16)a.w;
        v[4] = (_Float16)b.x; v[5] = (_Float16)b.y;
        v[6] = (_Float16)b.z; v[7] = (_Float16)b.w;
    } else {
#pragma unroll
        for (int j = 0; j < 8; ++j) v[j] = (_Float16)0.f;
    }
    *reinterpret_cast<f16x8*>(xh + (size_t)n * D + cx * 8) = v;
}

// ---------------------------------------------------------------------------
// Pass A: multisplit edges into 196 dst-range buckets per relation (unchanged).
// ---------------------------------------------------------------------------
__global__ __launch_bounds__(256)
void partition_kernel(const int* __restrict__ edges, int* __restrict__ gcnt,
                      uint* __restrict__ buckets, int* __restrict__ ovf_n,
                      int2* __restrict__ ovf) {
    __shared__ int hist[256], base[256], run[256], gbase[256], ps[256];
    __shared__ int tot_s;
    __shared__ uint staging[ECHUNK];
    const int t = threadIdx.x;
    const int r = blockIdx.y;
    const int* srcp = edges + (size_t)r * 2 * E;
    const int* dstp = srcp + E;
    const int e0 = blockIdx.x * ECHUNK;

    hist[t] = 0;
    run[t] = 0;
    __syncthreads();

    uint rec[16];
#pragma unroll
    for (int u = 0; u < 16; ++u) {
        const int i = e0 + u * 256 + t;
        if (i < E) {
            rec[u] = ((uint)srcp[i] << 16) | (uint)dstp[i];
            atomicAdd(&hist[(rec[u] & 0xFFFFu) >> 8], 1);
        } else {
            rec[u] = 0xFFFFFFFFu;  // invalid marker (src=65535 impossible)
        }
    }
    __syncthreads();

    const int v = hist[t];
    ps[t] = v;
    __syncthreads();
    for (int off = 1; off < 256; off <<= 1) {
        const int x = (t >= off) ? ps[t - off] : 0;
        __syncthreads();
        ps[t] += x;
        __syncthreads();
    }
    base[t] = ps[t] - v;
    if (t == 255) tot_s = ps[255];
    if (v > 0) gbase[t] = atomicAdd(&gcnt[r * NBPR + t], v);
    __syncthreads();

#pragma unroll
    for (int u = 0; u < 16; ++u) {
        if (rec[u] != 0xFFFFFFFFu) {
            const int bl = (rec[u] & 0xFFFFu) >> 8;
            const int pos = base[bl] + atomicAdd(&run[bl], 1);
            staging[pos] = rec[u];
        }
    }
    __syncthreads();

    const int total = tot_s;
    for (int j = t; j < total; j += 256) {
        const uint rc = staging[j];
        const int bl = (rc & 0xFFFFu) >> 8;
        const int gp = gbase[bl] + (j - base[bl]);
        if (gp < BCAP) {
            buckets[(size_t)(r * NBPR + bl) * BCAP + gp] = rc;
        } else {  // statistically never (11 sigma); correctness fallback
            const int o = atomicAdd(ovf_n, 1);
            if (o < MAXOVF)
                ovf[o] = make_int2(r * N + (int)(rc & 0xFFFFu), (int)(rc >> 16));
        }
    }
}

// ---------------------------------------------------------------------------
// Pass B fused with gather: one block per (bucket, 32-node PART) — halved
// granularity vs r13 so LDS ~19KB -> 8 blocks/CU (2x occupancy, 2x MLP).
// Hot loop identical to r13 (proven): 4-edge unrolled 512B row reads from
// row-major xh, LDS msg tile, then coalesced linear half-tile write-out.
// ---------------------------------------------------------------------------
__global__ __launch_bounds__(256)
void bucket_gather_kernel(const uint* __restrict__ buckets,
                          const int* __restrict__ gcnt,
                          const _Float16* __restrict__ xh,
                          const int2* __restrict__ ovf,
                          const int* __restrict__ ovf_n,
                          _Float16* __restrict__ A_t) {
    __shared__ int lcnt[32];
    __shared__ ushort lslots[32][MAXDEG];
    __shared__ _Float16 msg[32][264];   // padded: stride 528B
    const int t = threadIdx.x;
    const int b = blockIdx.x >> 3;       // bucket 0..783
    const int part = blockIdx.x & 7;     // 32-node part
    const int r = b / NBPR;
    const int bl = b - r * NBPR;
    const int d0 = (bl << 8) + (part << 5);
    if (d0 >= N) return;                 // whole part out of range
    const int mt = d0 >> 6;              // A_t m-tile
    const int rowoff = d0 & 63;          // 0 or 32 within the tile

    if (t < 32) lcnt[t] = 0;
    __syncthreads();

    const int nb = min(gcnt[b], BCAP);
    const uint* brec = buckets + (size_t)b * BCAP;
    for (int j = t; j < nb; j += 256) {
        const uint rc = brec[j];
        const int wi = (int)(rc & 0xFFFFu) - d0;
        if ((unsigned)wi < 32u) {
            const int pos = atomicAdd(&lcnt[wi], 1);
            if (pos < MAXDEG) lslots[wi][pos] = (ushort)(rc >> 16);
        }
    }
    __syncthreads();

    const int lane = t & 63;
    const int wv = t >> 6;           // wave 0..3 handles 8 nodes
    const int hf = lane >> 5;        // half-wave: even/odd edges
    const int cx = lane & 31;        // 16B chunk 0..31 of the 256-col row
    const int on = min(*ovf_n, MAXOVF);

    auto xrow = [&](int s) -> f16x8 {
        return *reinterpret_cast<const f16x8*>(xh + (size_t)s * D + cx * 8);
    };

    for (int wi = wv * 8; wi < wv * 8 + 8; ++wi) {
        const int d = d0 + wi;
        const int m = (d < N) ? lcnt[wi] : 0;
        float acc[8] = {};
        if (m <= MAXDEG) {
            int j = hf;
            // 4-edge unrolled batch: 4 independent 16B loads in flight
            for (; j + 6 < m; j += 8) {
                const int s0 = lslots[wi][j];
                const int s1 = lslots[wi][j + 2];
                const int s2 = lslots[wi][j + 4];
                const int s3 = lslots[wi][j + 6];
                const f16x8 v0 = xrow(s0);
                const f16x8 v1 = xrow(s1);
                const f16x8 v2 = xrow(s2);
                const f16x8 v3 = xrow(s3);
#pragma unroll
                for (int k = 0; k < 8; ++k)
                    acc[k] += ((float)v0[k] + (float)v1[k]) +
                              ((float)v2[k] + (float)v3[k]);
            }
            for (; j < m; j += 2) {
                const f16x8 vv = xrow(lslots[wi][j]);
#pragma unroll
                for (int k = 0; k < 8; ++k) acc[k] += (float)vv[k];
            }
        } else {  // slot overflow (never in practice): direct bucket scan
            for (int j = hf; j < nb; j += 2) {
                const uint rc = brec[j];
                if ((int)(rc & 0xFFFFu) == d) {
                    const f16x8 vv = xrow((int)(rc >> 16));
#pragma unroll
                    for (int k = 0; k < 8; ++k) acc[k] += (float)vv[k];
                }
            }
        }
        int ecnt = m;
        if (on > 0 && d < N) {
            const int wfull = r * N + d;
            for (int o = 0; o < on; ++o) {
                const int2 e2 = ovf[o];
                if (e2.x == wfull) {
                    ecnt++;
                    if (hf == 0) {
                        const f16x8 vv = xrow(e2.y);
#pragma unroll
                        for (int k = 0; k < 8; ++k) acc[k] += (float)vv[k];
                    }
                }
            }
        }
#pragma unroll
        for (int k = 0; k < 8; ++k) acc[k] += __shfl_xor(acc[k], 32);
        if (hf == 0) {
            const float rs = 1.0f / fmaxf((float)ecnt, 1.0f);
            f16x8 o8;
#pragma unroll
            for (int k = 0; k < 8; ++k) o8[k] = (_Float16)(acc[k] * rs);
            *reinterpret_cast<f16x8*>(&msg[wi][cx * 8]) = o8;
        }
    }
    __syncthreads();

    // cooperative linear write-out of the 16KB (mt, r, rowoff) half-region.
    // chunk g: plane q = g>>5 (0..31), row = g&31; dst = q*512 + (rowoff+row)*8.
    _Float16* dst = A_t + ((size_t)mt * 32 + r * 8) * 2048 + (size_t)rowoff * 8;
#pragma unroll
    for (int i = 0; i < 4; ++i) {
        const int g = i * 256 + t;
        const int row = g & 31;
        const int q = g >> 5;
        const int c = (q >> 2) * 32 + (q & 3) * 8;
        const f16x8 v = *reinterpret_cast<const f16x8*>(&msg[row][c]);
        *reinterpret_cast<f16x8*>(dst + (size_t)q * 512 + (size_t)row * 8) = v;
    }
}

// ---------------------------------------------------------------------------
// out[N,256] = tanh( [A_t | xh] @ WT_t^T + bias ), fp32 accum/out.
// BM=64, BN=128, BK=32, 4 waves. 3-buffer DEPTH-2 pipeline, counted vmcnt
// (3 loads/wave/stage; never 0 in main loop). kt<32: contiguous 1KB from
// tiled A_t; kt>=32: loop plane from row-major xh (8/40 steps, L3-resident).
// ---------------------------------------------------------------------------
__global__ __launch_bounds__(256)
void gemm_final_kernel(const _Float16* __restrict__ A_t,
                       const _Float16* __restrict__ xh,
                       const _Float16* __restrict__ WT_t,
                       const float* __restrict__ bias, float* __restrict__ C) {
    __shared__ _Float16 As[3][4][64][8];    // 3 x 4KB
    __shared__ _Float16 Bs[3][4][128][8];   // 3 x 8KB

    const int t = threadIdx.x;
    const int lane = t & 63;
    const int w = t >> 6;
    const int mt = blockIdx.x;           // 64-row m-tile
    const int nt = blockIdx.y;           // 128-col n-tile
    const long m0 = (long)mt * 64;

    f32x4 acc[8];
#pragma unroll
    for (int j = 0; j < 8; ++j) acc[j] = (f32x4){0.f, 0.f, 0.f, 0.f};

    const int kg = lane >> 4;
    const int rr = lane & 15;

    auto stage = [&](int kt, int buf) {
        const _Float16* asrc =
            (kt < 32)
                ? A_t + ((size_t)mt * 32 + kt) * 2048 + w * 512 + lane * 8
                : xh + (size_t)(m0 + lane) * D + (kt - 32) * 32 + w * 8;
        load_lds16(asrc, &As[buf][0][0][0] + w * 512);
        const _Float16* bsrc = WT_t + ((size_t)nt * 40 + kt) * 4096 + w * 1024 + lane * 8;
        load_lds16(bsrc, &Bs[buf][0][0][0] + w * 1024);
        load_lds16(bsrc + 512, &Bs[buf][0][0][0] + w * 1024 + 512);
    };

    auto compute = [&](int buf) {
        f16x8 af, bf[8];
        af = *reinterpret_cast<const f16x8*>(&As[buf][kg][w * 16 + rr][0]);
#pragma unroll
        for (int g = 0; g < 8; ++g)
            bf[g] = *reinterpret_cast<const f16x8*>(&Bs[buf][kg][g * 16 + rr][0]);
        __builtin_amdgcn_s_setprio(1);
#pragma unroll
        for (int j = 0; j < 8; ++j)
            acc[j] = __builtin_amdgcn_mfma_f32_16x16x32_f16(af, bf[j], acc[j], 0, 0, 0);
        __builtin_amdgcn_s_setprio(0);
    };

    // prologue: stage tiles 0,1 (6 loads in flight per wave)
    stage(0, 0);
    stage(1, 1);

    for (int kt = 0; kt < NT - 2; ++kt) {
        asm volatile("s_waitcnt vmcnt(3)" ::: "memory");  // tile kt landed
        __builtin_amdgcn_sched_barrier(0);
        __builtin_amdgcn_s_barrier();  // all waves: tile kt landed; compute(kt-1) done
        __builtin_amdgcn_sched_barrier(0);
        stage(kt + 2, (kt + 2) % 3);
        compute(kt % 3);
    }
    // kt = NT-2: only tile NT-1's 3 loads outstanding after this wait
    asm volatile("s_waitcnt vmcnt(3)" ::: "memory");
    __builtin_amdgcn_sched_barrier(0);
    __builtin_amdgcn_s_barrier();
    __builtin_amdgcn_sched_barrier(0);
    compute((NT - 2) % 3);
    // kt = NT-1
    asm volatile("s_waitcnt vmcnt(0)" ::: "memory");
    __builtin_amdgcn_sched_barrier(0);
    __builtin_amdgcn_s_barrier();
    __builtin_amdgcn_sched_barrier(0);
    compute((NT - 1) % 3);

    // epilogue: C/D map col=lane&15, row=(lane>>4)*4+reg
    const int crow0 = (lane >> 4) * 4;
    const int ccol = lane & 15;
    const long rowb = m0 + w * 16 + crow0;
#pragma unroll
    for (int j = 0; j < 8; ++j) {
        const int col = nt * 128 + j * 16 + ccol;
        const float b = bias[col];
#pragma unroll
        for (int q = 0; q < 4; ++q) {
            const long rgl = rowb + q;
            if (rgl < N) C[rgl * 256 + col] = fast_tanh(acc[j][q] + b);
        }
    }
}

// ---------------------------------------------------------------------------
extern "C" void kernel_launch(void* const* d_in, const int* in_sizes, int n_in,
                              void* d_out, int out_size, void* d_ws, size_t ws_size,
                              hipStream_t stream) {
    const float* x           = (const float*)d_in[0];
    const int*   edges       = (const int*)d_in[1];   // [4][2][400000] int32
    const float* weight      = (const float*)d_in[2]; // [4][256][256]
    const float* loop_weight = (const float*)d_in[3]; // [256][256]
    const float* h_bias      = (const float*)d_in[4]; // [256]
    float*       out         = (float*)d_out;
    (void)in_sizes; (void)n_in; (void)out_size; (void)ws_size;

    size_t off = 0;
    auto carve = [&](size_t bytes) -> void* {
        void* p = (char*)d_ws + off;
        off = (off + bytes + 255) & ~(size_t)255;
        return p;
    };

    _Float16* A_t  = (_Float16*)carve((size_t)MTILES * 32 * 2048 * sizeof(_Float16)); // 102.5 MB
    _Float16* xh   = (_Float16*)carve((size_t)AROWS * D * sizeof(_Float16));          // 25.6 MB
    _Float16* WT_t = (_Float16*)carve((size_t)2 * 40 * 4096 * sizeof(_Float16));      // 640 KB
    int*      gcnt  = (int*)carve((size_t)NBKT * sizeof(int));
    int*      ovf_n = (int*)carve(256);
    int2*     ovf   = (int2*)carve((size_t)MAXOVF * sizeof(int2));
    // ws total ~128.8 MB (proven available).
    // bucket array (8 MB) aliases d_out: dead before gemm_final overwrites it.
    uint* buckets = (uint*)d_out;  // NBKT*BCAP*4 = 8.03 MB <= 51.2 MB

    hipMemsetAsync(gcnt, 0, (size_t)NBKT * sizeof(int), stream);
    hipMemsetAsync(ovf_n, 0, sizeof(int), stream);

    wt_build_kernel<<<(40960 + 255) / 256, 256, 0, stream>>>(weight, loop_weight, WT_t);
    convert_x_kernel<<<((long)AROWS * 32 + 255) / 256, 256, 0, stream>>>(x, xh);

    // multisplit edges -> dst-range buckets
    partition_kernel<<<dim3(NCHUNKS, R), 256, 0, stream>>>(edges, gcnt, buckets,
                                                           ovf_n, ovf);
    // LDS slot build + gather fused (32-node parts, 8 blocks/CU)
    bucket_gather_kernel<<<NBKT * 8, 256, 0, stream>>>(buckets, gcnt, xh,
                                                       ovf, ovf_n, A_t);
    // out = tanh([A_t | xh] @ WT_t + bias)
    gemm_final_kernel<<<dim3(MTILES, 2), 256, 0, stream>>>(A_t, xh, WT_t, h_bias, out);
}

// Round 16
// 224.728 us; speedup vs baseline: 1.1741x; 1.0468x over previous
//
#include <hip/hip_runtime.h>
#include <cstdint>
#include <cstddef>

constexpr int N = 50000;      // nodes
constexpr int D = 256;        // D_IN == D_OUT
constexpr int E = 400000;     // edges per relation
constexpr int R = 4;          // relations
constexpr int AROWS = 50048;  // 782 * 64, padded M
constexpr int MTILES = AROWS / 64;  // 782
constexpr int KCAT = 1280;    // GEMM K = 4 msg planes + loop plane
constexpr int NT = KCAT / 32; // 40 K-steps

// Layouts:
//   A_t  [mt][kt 0..31][pl 0..3][row 0..63][8]  tiled msg planes  102.5 MB
//   xh   [AROWS][256] row-major fp16                              25.6 MB
//   WT_t [nt 0..1][kt 0..39][pl 0..3][row 0..127][8]              640 KB

constexpr int NBPR = 196;     // dst buckets per relation (ceil(N/256))
constexpr int NBKT = NBPR * R;        // 784
constexpr int BCAP = 2560;            // records per bucket (mean 2048, +11 sigma)
constexpr int MAXDEG = 32;            // LDS slots per node (P(Poi(8)>32) ~ 3e-12)
constexpr int ECHUNK = 4096;          // edges per partition block
constexpr int NCHUNKS = (E + ECHUNK - 1) / ECHUNK;  // 98
constexpr int MAXOVF = 4096;          // bucket-cap overflow list (never in practice)

constexpr int PART_BLOCKS = NCHUNKS * R;                 // 392
constexpr int CONV_BLOCKS = (AROWS * 32 + 255) / 256;    // 6256
constexpr int WT_BLOCKS = (2 * 40 * 4 * 128 + 255) / 256;  // 160
constexpr int PREP_BLOCKS = PART_BLOCKS + CONV_BLOCKS + WT_BLOCKS;

typedef _Float16 f16x8 __attribute__((ext_vector_type(8)));
typedef float f32x4 __attribute__((ext_vector_type(4)));

__device__ __forceinline__ void load_lds16(const void* g, void* l) {
    __builtin_amdgcn_global_load_lds(
        (const __attribute__((address_space(1))) void*)g,
        (__attribute__((address_space(3))) void*)l, 16, 0, 0);
}

__device__ __forceinline__ float fast_tanh(float x) {
    const float xc = fminf(fmaxf(x, -9.0f), 9.0f);
    const float t = __builtin_amdgcn_exp2f(xc * 2.8853900817779268f);  // e^{2x}
    return (t - 1.0f) / (t + 1.0f);
}

// ---------------------------------------------------------------------------
// Fused prep: blockIdx-split into {partition | convert | wt_build}; the three
// are independent, so they overlap inside one dispatch (partition blocks
// first: they are the long pole). Bodies identical to r15's kernels.
// ---------------------------------------------------------------------------
__global__ __launch_bounds__(256)
void prep_kernel(const float* __restrict__ x, const int* __restrict__ edges,
                 const float* __restrict__ w, const float* __restrict__ lw,
                 _Float16* __restrict__ xh, _Float16* __restrict__ wt,
                 int* __restrict__ gcnt, uint* __restrict__ buckets,
                 int* __restrict__ ovf_n, int2* __restrict__ ovf) {
    __shared__ int hist[256], base[256], run[256], gbase[256], ps[256];
    __shared__ int tot_s;
    __shared__ uint staging[ECHUNK];

    const int bid = blockIdx.x;
    const int t = threadIdx.x;

    if (bid < PART_BLOCKS) {
        // ---- partition: multisplit edges into dst-range buckets
        const int chunk = bid >> 2;
        const int r = bid & 3;
        const int* srcp = edges + (size_t)r * 2 * E;
        const int* dstp = srcp + E;
        const int e0 = chunk * ECHUNK;

        hist[t] = 0;
        run[t] = 0;
        __syncthreads();

        uint rec[16];
#pragma unroll
        for (int u = 0; u < 16; ++u) {
            const int i = e0 + u * 256 + t;
            if (i < E) {
                rec[u] = ((uint)srcp[i] << 16) | (uint)dstp[i];
                atomicAdd(&hist[(rec[u] & 0xFFFFu) >> 8], 1);
            } else {
                rec[u] = 0xFFFFFFFFu;  // invalid marker (src=65535 impossible)
            }
        }
        __syncthreads();

        const int v = hist[t];
        ps[t] = v;
        __syncthreads();
        for (int off = 1; off < 256; off <<= 1) {
            const int xx = (t >= off) ? ps[t - off] : 0;
            __syncthreads();
            ps[t] += xx;
            __syncthreads();
        }
        base[t] = ps[t] - v;
        if (t == 255) tot_s = ps[255];
        if (v > 0) gbase[t] = atomicAdd(&gcnt[r * NBPR + t], v);
        __syncthreads();

#pragma unroll
        for (int u = 0; u < 16; ++u) {
            if (rec[u] != 0xFFFFFFFFu) {
                const int bl = (rec[u] & 0xFFFFu) >> 8;
                const int pos = base[bl] + atomicAdd(&run[bl], 1);
                staging[pos] = rec[u];
            }
        }
        __syncthreads();

        const int total = tot_s;
        for (int j = t; j < total; j += 256) {
            const uint rc = staging[j];
            const int bl = (rc & 0xFFFFu) >> 8;
            const int gp = gbase[bl] + (j - base[bl]);
            if (gp < BCAP) {
                buckets[(size_t)(r * NBPR + bl) * BCAP + gp] = rc;
            } else {  // statistically never (11 sigma); correctness fallback
                const int o = atomicAdd(ovf_n, 1);
                if (o < MAXOVF)
                    ovf[o] = make_int2(r * N + (int)(rc & 0xFFFFu), (int)(rc >> 16));
            }
        }
    } else if (bid < PART_BLOCKS + CONV_BLOCKS) {
        // ---- convert: x fp32 -> row-major fp16 xh; rows >= N zeroed
        const long i = (long)(bid - PART_BLOCKS) * 256 + t;
        if (i >= (long)AROWS * 32) return;
        const int n = (int)(i >> 5);
        const int cx = (int)(i & 31);
        f16x8 vv;
        if (n < N) {
            const float4* s =
                reinterpret_cast<const float4*>(x + (size_t)n * D + cx * 8);
            const float4 a = s[0], b = s[1];
            vv[0] = (_Float16)a.x; vv[1] = (_Float16)a.y;
            vv[2] = (_Float16)a.z; vv[3] = (_Float16)a.w;
            vv[4] = (_Float16)b.x; vv[5] = (_Float16)b.y;
            vv[6] = (_Float16)b.z; vv[7] = (_Float16)b.w;
        } else {
#pragma unroll
            for (int j = 0; j < 8; ++j) vv[j] = (_Float16)0.f;
        }
        *reinterpret_cast<f16x8*>(xh + (size_t)n * D + cx * 8) = vv;
    } else {
        // ---- wt_build: tiled fp16 weights, linear write
        const int i = (bid - PART_BLOCKS - CONV_BLOCKS) * 256 + t;
        if (i >= 2 * 40 * 4 * 128) return;
        const int nt = i / 20480;
        const int r1 = i - nt * 20480;
        const int kt = r1 >> 9;
        const int r2 = r1 & 511;
        const int pl = r2 >> 7;
        const int row = r2 & 127;
        const int kb = kt * 32 + pl * 8;
        const int col = nt * 128 + row;
        f16x8 vv;
#pragma unroll
        for (int j = 0; j < 8; ++j) {
            const int k = kb + j;
            const float val = (k < 1024)
                                  ? w[((k >> 8) << 16) + ((k & 255) << 8) + col]
                                  : lw[((k - 1024) << 8) + col];
            vv[j] = (_Float16)val;
        }
        *reinterpret_cast<f16x8*>(wt + (size_t)i * 8) = vv;
    }
}

// ---------------------------------------------------------------------------
// Pass B fused with gather: one block per (bucket, 32-node PART); ~19KB LDS
// -> 8 blocks/CU. 4-edge unrolled 512B row reads from row-major xh, LDS msg
// tile, coalesced linear half-tile write-out. (r15-proven, unchanged.)
// ---------------------------------------------------------------------------
__global__ __launch_bounds__(256)
void bucket_gather_kernel(const uint* __restrict__ buckets,
                          const int* __restrict__ gcnt,
                          const _Float16* __restrict__ xh,
                          const int2* __restrict__ ovf,
                          const int* __restrict__ ovf_n,
                          _Float16* __restrict__ A_t) {
    __shared__ int lcnt[32];
    __shared__ ushort lslots[32][MAXDEG];
    __shared__ _Float16 msg[32][264];   // padded: stride 528B
    const int t = threadIdx.x;
    const int b = blockIdx.x >> 3;       // bucket 0..783
    const int part = blockIdx.x & 7;     // 32-node part
    const int r = b / NBPR;
    const int bl = b - r * NBPR;
    const int d0 = (bl << 8) + (part << 5);
    if (d0 >= N) return;                 // whole part out of range
    const int mt = d0 >> 6;              // A_t m-tile
    const int rowoff = d0 & 63;          // 0 or 32 within the tile

    if (t < 32) lcnt[t] = 0;
    __syncthreads();

    const int nb = min(gcnt[b], BCAP);
    const uint* brec = buckets + (size_t)b * BCAP;
    for (int j = t; j < nb; j += 256) {
        const uint rc = brec[j];
        const int wi = (int)(rc & 0xFFFFu) - d0;
        if ((unsigned)wi < 32u) {
            const int pos = atomicAdd(&lcnt[wi], 1);
            if (pos < MAXDEG) lslots[wi][pos] = (ushort)(rc >> 16);
        }
    }
    __syncthreads();

    const int lane = t & 63;
    const int wv = t >> 6;           // wave 0..3 handles 8 nodes
    const int hf = lane >> 5;        // half-wave: even/odd edges
    const int cx = lane & 31;        // 16B chunk 0..31 of the 256-col row
    const int on = min(*ovf_n, MAXOVF);

    auto xrow = [&](int s) -> f16x8 {
        return *reinterpret_cast<const f16x8*>(xh + (size_t)s * D + cx * 8);
    };

    for (int wi = wv * 8; wi < wv * 8 + 8; ++wi) {
        const int d = d0 + wi;
        const int m = (d < N) ? lcnt[wi] : 0;
        float acc[8] = {};
        if (m <= MAXDEG) {
            int j = hf;
            for (; j + 6 < m; j += 8) {
                const int s0 = lslots[wi][j];
                const int s1 = lslots[wi][j + 2];
                const int s2 = lslots[wi][j + 4];
                const int s3 = lslots[wi][j + 6];
                const f16x8 v0 = xrow(s0);
                const f16x8 v1 = xrow(s1);
                const f16x8 v2 = xrow(s2);
                const f16x8 v3 = xrow(s3);
#pragma unroll
                for (int k = 0; k < 8; ++k)
                    acc[k] += ((float)v0[k] + (float)v1[k]) +
                              ((float)v2[k] + (float)v3[k]);
            }
            for (; j < m; j += 2) {
                const f16x8 vv = xrow(lslots[wi][j]);
#pragma unroll
                for (int k = 0; k < 8; ++k) acc[k] += (float)vv[k];
            }
        } else {  // slot overflow (never in practice): direct bucket scan
            for (int j = hf; j < nb; j += 2) {
                const uint rc = brec[j];
                if ((int)(rc & 0xFFFFu) == d) {
                    const f16x8 vv = xrow((int)(rc >> 16));
#pragma unroll
                    for (int k = 0; k < 8; ++k) acc[k] += (float)vv[k];
                }
            }
        }
        int ecnt = m;
        if (on > 0 && d < N) {
            const int wfull = r * N + d;
            for (int o = 0; o < on; ++o) {
                const int2 e2 = ovf[o];
                if (e2.x == wfull) {
                    ecnt++;
                    if (hf == 0) {
                        const f16x8 vv = xrow(e2.y);
#pragma unroll
                        for (int k = 0; k < 8; ++k) acc[k] += (float)vv[k];
                    }
                }
            }
        }
#pragma unroll
        for (int k = 0; k < 8; ++k) acc[k] += __shfl_xor(acc[k], 32);
        if (hf == 0) {
            const float rs = 1.0f / fmaxf((float)ecnt, 1.0f);
            f16x8 o8;
#pragma unroll
            for (int k = 0; k < 8; ++k) o8[k] = (_Float16)(acc[k] * rs);
            *reinterpret_cast<f16x8*>(&msg[wi][cx * 8]) = o8;
        }
    }
    __syncthreads();

    // cooperative linear write-out of the 16KB (mt, r, rowoff) half-region.
    _Float16* dst = A_t + ((size_t)mt * 32 + r * 8) * 2048 + (size_t)rowoff * 8;
#pragma unroll
    for (int i = 0; i < 4; ++i) {
        const int g = i * 256 + t;
        const int row = g & 31;
        const int q = g >> 5;
        const int c = (q >> 2) * 32 + (q & 3) * 8;
        const f16x8 v = *reinterpret_cast<const f16x8*>(&msg[row][c]);
        *reinterpret_cast<f16x8*>(dst + (size_t)q * 512 + (size_t)row * 8) = v;
    }
}

// ---------------------------------------------------------------------------
// out[N,256] = tanh( [A_t | xh] @ WT_t^T + bias ), fp32 accum/out.
// BM=64, BN=128, BK=32, 4 waves. 3-buffer DEPTH-2 pipeline, counted vmcnt.
// GRID (2, MTILES): the two n-tile blocks of an m-tile are dispatch-adjacent,
// so the second reads A_t[mt] from L2/L3 instead of HBM (A-read pairing).
// ---------------------------------------------------------------------------
__global__ __launch_bounds__(256)
void gemm_final_kernel(const _Float16* __restrict__ A_t,
                       const _Float16* __restrict__ xh,
                       const _Float16* __restrict__ WT_t,
                       const float* __restrict__ bias, float* __restrict__ C) {
    __shared__ _Float16 As[3][4][64][8];    // 3 x 4KB
    __shared__ _Float16 Bs[3][4][128][8];   // 3 x 8KB

    const int t = threadIdx.x;
    const int lane = t & 63;
    const int w = t >> 6;
    const int nt = blockIdx.x;           // 128-col n-tile (fast dim)
    const int mt = blockIdx.y;           // 64-row m-tile
    const long m0 = (long)mt * 64;

    f32x4 acc[8];
#pragma unroll
    for (int j = 0; j < 8; ++j) acc[j] = (f32x4){0.f, 0.f, 0.f, 0.f};

    const int kg = lane >> 4;
    const int rr = lane & 15;

    auto stage = [&](int kt, int buf) {
        const _Float16* asrc =
            (kt < 32)
                ? A_t + ((size_t)mt * 32 + kt) * 2048 + w * 512 + lane * 8
                : xh + (size_t)(m0 + lane) * D + (kt - 32) * 32 + w * 8;
        load_lds16(asrc, &As[buf][0][0][0] + w * 512);
        const _Float16* bsrc = WT_t + ((size_t)nt * 40 + kt) * 4096 + w * 1024 + lane * 8;
        load_lds16(bsrc, &Bs[buf][0][0][0] + w * 1024);
        load_lds16(bsrc + 512, &Bs[buf][0][0][0] + w * 1024 + 512);
    };

    auto compute = [&](int buf) {
        f16x8 af, bf[8];
        af = *reinterpret_cast<const f16x8*>(&As[buf][kg][w * 16 + rr][0]);
#pragma unroll
        for (int g = 0; g < 8; ++g)
            bf[g] = *reinterpret_cast<const f16x8*>(&Bs[buf][kg][g * 16 + rr][0]);
        __builtin_amdgcn_s_setprio(1);
#pragma unroll
        for (int j = 0; j < 8; ++j)
            acc[j] = __builtin_amdgcn_mfma_f32_16x16x32_f16(af, bf[j], acc[j], 0, 0, 0);
        __builtin_amdgcn_s_setprio(0);
    };

    // prologue: stage tiles 0,1 (6 loads in flight per wave)
    stage(0, 0);
    stage(1, 1);

    for (int kt = 0; kt < NT - 2; ++kt) {
        asm volatile("s_waitcnt vmcnt(3)" ::: "memory");  // tile kt landed
        __builtin_amdgcn_sched_barrier(0);
        __builtin_amdgcn_s_barrier();  // all waves: tile kt landed; compute(kt-1) done
        __builtin_amdgcn_sched_barrier(0);
        stage(kt + 2, (kt + 2) % 3);
        compute(kt % 3);
    }
    // kt = NT-2
    asm volatile("s_waitcnt vmcnt(3)" ::: "memory");
    __builtin_amdgcn_sched_barrier(0);
    __builtin_amdgcn_s_barrier();
    __builtin_amdgcn_sched_barrier(0);
    compute((NT - 2) % 3);
    // kt = NT-1
    asm volatile("s_waitcnt vmcnt(0)" ::: "memory");
    __builtin_amdgcn_sched_barrier(0);
    __builtin_amdgcn_s_barrier();
    __builtin_amdgcn_sched_barrier(0);
    compute((NT - 1) % 3);

    // epilogue: C/D map col=lane&15, row=(lane>>4)*4+reg
    const int crow0 = (lane >> 4) * 4;
    const int ccol = lane & 15;
    const long rowb = m0 + w * 16 + crow0;
#pragma unroll
    for (int j = 0; j < 8; ++j) {
        const int col = nt * 128 + j * 16 + ccol;
        const float b = bias[col];
#pragma unroll
        for (int q = 0; q < 4; ++q) {
            const long rgl = rowb + q;
            if (rgl < N) C[rgl * 256 + col] = fast_tanh(acc[j][q] + b);
        }
    }
}

// ---------------------------------------------------------------------------
extern "C" void kernel_launch(void* const* d_in, const int* in_sizes, int n_in,
                              void* d_out, int out_size, void* d_ws, size_t ws_size,
                              hipStream_t stream) {
    const float* x           = (const float*)d_in[0];
    const int*   edges       = (const int*)d_in[1];   // [4][2][400000] int32
    const float* weight      = (const float*)d_in[2]; // [4][256][256]
    const float* loop_weight = (const float*)d_in[3]; // [256][256]
    const float* h_bias      = (const float*)d_in[4]; // [256]
    float*       out         = (float*)d_out;
    (void)in_sizes; (void)n_in; (void)out_size; (void)ws_size;

    size_t off = 0;
    auto carve = [&](size_t bytes) -> void* {
        void* p = (char*)d_ws + off;
        off = (off + bytes + 255) & ~(size_t)255;
        return p;
    };

    _Float16* A_t  = (_Float16*)carve((size_t)MTILES * 32 * 2048 * sizeof(_Float16)); // 102.5 MB
    _Float16* xh   = (_Float16*)carve((size_t)AROWS * D * sizeof(_Float16));          // 25.6 MB
    _Float16* WT_t = (_Float16*)carve((size_t)2 * 40 * 4096 * sizeof(_Float16));      // 640 KB
    int*      gcnt  = (int*)carve((size_t)NBKT * sizeof(int) + 256);  // +ovf_n in tail
    int*      ovf_n = gcnt + NBKT;
    int2*     ovf   = (int2*)carve((size_t)MAXOVF * sizeof(int2));
    // ws total ~128.8 MB (proven available).
    // bucket array (8 MB) aliases d_out: dead before gemm_final overwrites it.
    uint* buckets = (uint*)d_out;  // NBKT*BCAP*4 = 8.03 MB <= 51.2 MB

    // one memset covers gcnt and ovf_n (adjacent carve)
    hipMemsetAsync(gcnt, 0, (size_t)NBKT * sizeof(int) + 256, stream);

    // fused prep: partition + convert + wt_build in one dispatch
    prep_kernel<<<PREP_BLOCKS, 256, 0, stream>>>(x, edges, weight, loop_weight,
                                                 xh, WT_t, gcnt, buckets,
                                                 ovf_n, ovf);

    // LDS slot build + gather fused (32-node parts, 8 blocks/CU)
    bucket_gather_kernel<<<NBKT * 8, 256, 0, stream>>>(buckets, gcnt, xh,
                                                       ovf, ovf_n, A_t);
    // out = tanh([A_t | xh] @ WT_t + bias)
    gemm_final_kernel<<<dim3(2, MTILES), 256, 0, stream>>>(A_t, xh, WT_t, h_bias, out);
}

// Round 17
// 221.651 us; speedup vs baseline: 1.1904x; 1.0139x over previous
//
#include <hip/hip_runtime.h>
#include <cstdint>
#include <cstddef>

constexpr int N = 50000;      // nodes
constexpr int D = 256;        // D_IN == D_OUT
constexpr int E = 400000;     // edges per relation
constexpr int R = 4;          // relations
constexpr int AROWS = 50048;  // 782 * 64, padded M
constexpr int MTILES = AROWS / 64;  // 782
constexpr int KCAT = 1280;    // GEMM K = 4 msg planes + loop plane
constexpr int NT = KCAT / 32; // 40 K-steps

// Layouts:
//   A_t  [mt][kt 0..31][pl 0..3][row 0..63][8]  tiled msg planes  102.5 MB
//   xh   [AROWS][256] row-major fp16                              25.6 MB
//   WT_t [nt 0..1][kt 0..39][pl 0..3][row 0..127][8]              640 KB

constexpr int NBPR = 196;     // dst buckets per relation (ceil(N/256))
constexpr int NBKT = NBPR * R;        // 784
constexpr int BCAP = 2560;            // records per bucket (mean 2048, +11 sigma)
constexpr int MAXDEG = 32;            // LDS slots per node (P(Poi(8)>32) ~ 3e-12)
constexpr int ECHUNK = 2048;          // edges per partition block (r17: halved)
constexpr int NCHUNKS = (E + ECHUNK - 1) / ECHUNK;  // 196
constexpr int MAXOVF = 4096;          // bucket-cap overflow list (never in practice)

constexpr int PART_BLOCKS = NCHUNKS * R;                 // 784 (~3/CU)
constexpr int CONV_BLOCKS = (AROWS * 32 + 255) / 256;    // 6256
constexpr int WT_BLOCKS = (2 * 40 * 4 * 128 + 255) / 256;  // 160
constexpr int PREP_BLOCKS = PART_BLOCKS + CONV_BLOCKS + WT_BLOCKS;

typedef _Float16 f16x8 __attribute__((ext_vector_type(8)));
typedef float f32x4 __attribute__((ext_vector_type(4)));

__device__ __forceinline__ void load_lds16(const void* g, void* l) {
    __builtin_amdgcn_global_load_lds(
        (const __attribute__((address_space(1))) void*)g,
        (__attribute__((address_space(3))) void*)l, 16, 0, 0);
}

__device__ __forceinline__ float fast_tanh(float x) {
    const float xc = fminf(fmaxf(x, -9.0f), 9.0f);
    const float t = __builtin_amdgcn_exp2f(xc * 2.8853900817779268f);  // e^{2x}
    return (t - 1.0f) / (t + 1.0f);
}

// ---------------------------------------------------------------------------
// Fused prep: blockIdx-split into {partition | convert | wt_build}.
// Partition blocks first (long pole). ECHUNK=2048 -> 784 partition blocks
// (~3/CU) halves the latency-exposed per-block critical path vs r16.
// ---------------------------------------------------------------------------
__global__ __launch_bounds__(256)
void prep_kernel(const float* __restrict__ x, const int* __restrict__ edges,
                 const float* __restrict__ w, const float* __restrict__ lw,
                 _Float16* __restrict__ xh, _Float16* __restrict__ wt,
                 int* __restrict__ gcnt, uint* __restrict__ buckets,
                 int* __restrict__ ovf_n, int2* __restrict__ ovf) {
    __shared__ int hist[256], base[256], run[256], gbase[256], ps[256];
    __shared__ int tot_s;
    __shared__ uint staging[ECHUNK];

    const int bid = blockIdx.x;
    const int t = threadIdx.x;

    if (bid < PART_BLOCKS) {
        // ---- partition: multisplit edges into dst-range buckets
        const int chunk = bid >> 2;
        const int r = bid & 3;
        const int* srcp = edges + (size_t)r * 2 * E;
        const int* dstp = srcp + E;
        const int e0 = chunk * ECHUNK;

        hist[t] = 0;
        run[t] = 0;
        __syncthreads();

        uint rec[8];
#pragma unroll
        for (int u = 0; u < 8; ++u) {
            const int i = e0 + u * 256 + t;
            if (i < E) {
                rec[u] = ((uint)srcp[i] << 16) | (uint)dstp[i];
                atomicAdd(&hist[(rec[u] & 0xFFFFu) >> 8], 1);
            } else {
                rec[u] = 0xFFFFFFFFu;  // invalid marker (src=65535 impossible)
            }
        }
        __syncthreads();

        const int v = hist[t];
        ps[t] = v;
        __syncthreads();
        for (int off = 1; off < 256; off <<= 1) {
            const int xx = (t >= off) ? ps[t - off] : 0;
            __syncthreads();
            ps[t] += xx;
            __syncthreads();
        }
        base[t] = ps[t] - v;
        if (t == 255) tot_s = ps[255];
        if (v > 0) gbase[t] = atomicAdd(&gcnt[r * NBPR + t], v);
        __syncthreads();

#pragma unroll
        for (int u = 0; u < 8; ++u) {
            if (rec[u] != 0xFFFFFFFFu) {
                const int bl = (rec[u] & 0xFFFFu) >> 8;
                const int pos = base[bl] + atomicAdd(&run[bl], 1);
                staging[pos] = rec[u];
            }
        }
        __syncthreads();

        const int total = tot_s;
        for (int j = t; j < total; j += 256) {
            const uint rc = staging[j];
            const int bl = (rc & 0xFFFFu) >> 8;
            const int gp = gbase[bl] + (j - base[bl]);
            if (gp < BCAP) {
                buckets[(size_t)(r * NBPR + bl) * BCAP + gp] = rc;
            } else {  // statistically never (11 sigma); correctness fallback
                const int o = atomicAdd(ovf_n, 1);
                if (o < MAXOVF)
                    ovf[o] = make_int2(r * N + (int)(rc & 0xFFFFu), (int)(rc >> 16));
            }
        }
    } else if (bid < PART_BLOCKS + CONV_BLOCKS) {
        // ---- convert: x fp32 -> row-major fp16 xh; rows >= N zeroed
        const long i = (long)(bid - PART_BLOCKS) * 256 + t;
        if (i >= (long)AROWS * 32) return;
        const int n = (int)(i >> 5);
        const int cx = (int)(i & 31);
        f16x8 vv;
        if (n < N) {
            const float4* s =
                reinterpret_cast<const float4*>(x + (size_t)n * D + cx * 8);
            const float4 a = s[0], b = s[1];
            vv[0] = (_Float16)a.x; vv[1] = (_Float16)a.y;
            vv[2] = (_Float16)a.z; vv[3] = (_Float16)a.w;
            vv[4] = (_Float16)b.x; vv[5] = (_Float16)b.y;
            vv[6] = (_Float16)b.z; vv[7] = (_Float16)b.w;
        } else {
#pragma unroll
            for (int j = 0; j < 8; ++j) vv[j] = (_Float16)0.f;
        }
        *reinterpret_cast<f16x8*>(xh + (size_t)n * D + cx * 8) = vv;
    } else {
        // ---- wt_build: tiled fp16 weights, linear write
        const int i = (bid - PART_BLOCKS - CONV_BLOCKS) * 256 + t;
        if (i >= 2 * 40 * 4 * 128) return;
        const int nt = i / 20480;
        const int r1 = i - nt * 20480;
        const int kt = r1 >> 9;
        const int r2 = r1 & 511;
        const int pl = r2 >> 7;
        const int row = r2 & 127;
        const int kb = kt * 32 + pl * 8;
        const int col = nt * 128 + row;
        f16x8 vv;
#pragma unroll
        for (int j = 0; j < 8; ++j) {
            const int k = kb + j;
            const float val = (k < 1024)
                                  ? w[((k >> 8) << 16) + ((k & 255) << 8) + col]
                                  : lw[((k - 1024) << 8) + col];
            vv[j] = (_Float16)val;
        }
        *reinterpret_cast<f16x8*>(wt + (size_t)i * 8) = vv;
    }
}

// ---------------------------------------------------------------------------
// Pass B fused with gather: one block per (bucket, 32-node PART); ~13KB LDS.
// bid decode b = bid % NBKT, part = bid / NBKT: since NBKT % 8 == 0, all 8
// parts of a bucket get bid%8 = b%8 -> same XCD under round-robin dispatch
// (perf-only assumption) -> 7/8 bucket re-reads become L2 hits, and A_t
// writes of one dst range stay in one XCD's L2.
// Hot loop identical to r15/r16 (proven).
// ---------------------------------------------------------------------------
__global__ __launch_bounds__(256)
void bucket_gather_kernel(const uint* __restrict__ buckets,
                          const int* __restrict__ gcnt,
                          const _Float16* __restrict__ xh,
                          const int2* __restrict__ ovf,
                          const int* __restrict__ ovf_n,
                          _Float16* __restrict__ A_t) {
    __shared__ int lcnt[32];
    __shared__ ushort lslots[32][MAXDEG];
    __shared__ _Float16 msg[32][264];   // padded: stride 528B
    const int t = threadIdx.x;
    const int b = blockIdx.x % NBKT;     // bucket 0..783 (same-XCD parts)
    const int part = blockIdx.x / NBKT;  // 32-node part 0..7
    const int r = b / NBPR;
    const int bl = b - r * NBPR;
    const int d0 = (bl << 8) + (part << 5);
    if (d0 >= N) return;                 // whole part out of range
    const int mt = d0 >> 6;              // A_t m-tile
    const int rowoff = d0 & 63;          // 0 or 32 within the tile

    if (t < 32) lcnt[t] = 0;
    __syncthreads();

    const int nb = min(gcnt[b], BCAP);
    const uint* brec = buckets + (size_t)b * BCAP;
    for (int j = t; j < nb; j += 256) {
        const uint rc = brec[j];
        const int wi = (int)(rc & 0xFFFFu) - d0;
        if ((unsigned)wi < 32u) {
            const int pos = atomicAdd(&lcnt[wi], 1);
            if (pos < MAXDEG) lslots[wi][pos] = (ushort)(rc >> 16);
        }
    }
    __syncthreads();

    const int lane = t & 63;
    const int wv = t >> 6;           // wave 0..3 handles 8 nodes
    const int hf = lane >> 5;        // half-wave: even/odd edges
    const int cx = lane & 31;        // 16B chunk 0..31 of the 256-col row
    const int on = min(*ovf_n, MAXOVF);

    auto xrow = [&](int s) -> f16x8 {
        return *reinterpret_cast<const f16x8*>(xh + (size_t)s * D + cx * 8);
    };

    for (int wi = wv * 8; wi < wv * 8 + 8; ++wi) {
        const int d = d0 + wi;
        const int m = (d < N) ? lcnt[wi] : 0;
        float acc[8] = {};
        if (m <= MAXDEG) {
            int j = hf;
            for (; j + 6 < m; j += 8) {
                const int s0 = lslots[wi][j];
                const int s1 = lslots[wi][j + 2];
                const int s2 = lslots[wi][j + 4];
                const int s3 = lslots[wi][j + 6];
                const f16x8 v0 = xrow(s0);
                const f16x8 v1 = xrow(s1);
                const f16x8 v2 = xrow(s2);
                const f16x8 v3 = xrow(s3);
#pragma unroll
                for (int k = 0; k < 8; ++k)
                    acc[k] += ((float)v0[k] + (float)v1[k]) +
                              ((float)v2[k] + (float)v3[k]);
            }
            for (; j < m; j += 2) {
                const f16x8 vv = xrow(lslots[wi][j]);
#pragma unroll
                for (int k = 0; k < 8; ++k) acc[k] += (float)vv[k];
            }
        } else {  // slot overflow (never in practice): direct bucket scan
            for (int j = hf; j < nb; j += 2) {
                const uint rc = brec[j];
                if ((int)(rc & 0xFFFFu) == d) {
                    const f16x8 vv = xrow((int)(rc >> 16));
#pragma unroll
                    for (int k = 0; k < 8; ++k) acc[k] += (float)vv[k];
                }
            }
        }
        int ecnt = m;
        if (on > 0 && d < N) {
            const int wfull = r * N + d;
            for (int o = 0; o < on; ++o) {
                const int2 e2 = ovf[o];
                if (e2.x == wfull) {
                    ecnt++;
                    if (hf == 0) {
                        const f16x8 vv = xrow(e2.y);
#pragma unroll
                        for (int k = 0; k < 8; ++k) acc[k] += (float)vv[k];
                    }
                }
            }
        }
#pragma unroll
        for (int k = 0; k < 8; ++k) acc[k] += __shfl_xor(acc[k], 32);
        if (hf == 0) {
            const float rs = 1.0f / fmaxf((float)ecnt, 1.0f);
            f16x8 o8;
#pragma unroll
            for (int k = 0; k < 8; ++k) o8[k] = (_Float16)(acc[k] * rs);
            *reinterpret_cast<f16x8*>(&msg[wi][cx * 8]) = o8;
        }
    }
    __syncthreads();

    // cooperative linear write-out of the 16KB (mt, r, rowoff) half-region.
    _Float16* dst = A_t + ((size_t)mt * 32 + r * 8) * 2048 + (size_t)rowoff * 8;
#pragma unroll
    for (int i = 0; i < 4; ++i) {
        const int g = i * 256 + t;
        const int row = g & 31;
        const int q = g >> 5;
        const int c = (q >> 2) * 32 + (q & 3) * 8;
        const f16x8 v = *reinterpret_cast<const f16x8*>(&msg[row][c]);
        *reinterpret_cast<f16x8*>(dst + (size_t)q * 512 + (size_t)row * 8) = v;
    }
}

// ---------------------------------------------------------------------------
// out[N,256] = tanh( [A_t | xh] @ WT_t^T + bias ), fp32 accum/out.
// BM=64, BN=128, BK=32, 4 waves. 3-buffer DEPTH-2 pipeline, counted vmcnt.
// GRID (2, MTILES): n-tile pair of an m-tile dispatch-adjacent (A L2 reuse).
// ---------------------------------------------------------------------------
__global__ __launch_bounds__(256)
void gemm_final_kernel(const _Float16* __restrict__ A_t,
                       const _Float16* __restrict__ xh,
                       const _Float16* __restrict__ WT_t,
                       const float* __restrict__ bias, float* __restrict__ C) {
    __shared__ _Float16 As[3][4][64][8];    // 3 x 4KB
    __shared__ _Float16 Bs[3][4][128][8];   // 3 x 8KB

    const int t = threadIdx.x;
    const int lane = t & 63;
    const int w = t >> 6;
    const int nt = blockIdx.x;           // 128-col n-tile (fast dim)
    const int mt = blockIdx.y;           // 64-row m-tile
    const long m0 = (long)mt * 64;

    f32x4 acc[8];
#pragma unroll
    for (int j = 0; j < 8; ++j) acc[j] = (f32x4){0.f, 0.f, 0.f, 0.f};

    const int kg = lane >> 4;
    const int rr = lane & 15;

    auto stage = [&](int kt, int buf) {
        const _Float16* asrc =
            (kt < 32)
                ? A_t + ((size_t)mt * 32 + kt) * 2048 + w * 512 + lane * 8
                : xh + (size_t)(m0 + lane) * D + (kt - 32) * 32 + w * 8;
        load_lds16(asrc, &As[buf][0][0][0] + w * 512);
        const _Float16* bsrc = WT_t + ((size_t)nt * 40 + kt) * 4096 + w * 1024 + lane * 8;
        load_lds16(bsrc, &Bs[buf][0][0][0] + w * 1024);
        load_lds16(bsrc + 512, &Bs[buf][0][0][0] + w * 1024 + 512);
    };

    auto compute = [&](int buf) {
        f16x8 af, bf[8];
        af = *reinterpret_cast<const f16x8*>(&As[buf][kg][w * 16 + rr][0]);
#pragma unroll
        for (int g = 0; g < 8; ++g)
            bf[g] = *reinterpret_cast<const f16x8*>(&Bs[buf][kg][g * 16 + rr][0]);
        __builtin_amdgcn_s_setprio(1);
#pragma unroll
        for (int j = 0; j < 8; ++j)
            acc[j] = __builtin_amdgcn_mfma_f32_16x16x32_f16(af, bf[j], acc[j], 0, 0, 0);
        __builtin_amdgcn_s_setprio(0);
    };

    // prologue: stage tiles 0,1 (6 loads in flight per wave)
    stage(0, 0);
    stage(1, 1);

    for (int kt = 0; kt < NT - 2; ++kt) {
        asm volatile("s_waitcnt vmcnt(3)" ::: "memory");  // tile kt landed
        __builtin_amdgcn_sched_barrier(0);
        __builtin_amdgcn_s_barrier();  // all waves: tile kt landed; compute(kt-1) done
        __builtin_amdgcn_sched_barrier(0);
        stage(kt + 2, (kt + 2) % 3);
        compute(kt % 3);
    }
    // kt = NT-2
    asm volatile("s_waitcnt vmcnt(3)" ::: "memory");
    __builtin_amdgcn_sched_barrier(0);
    __builtin_amdgcn_s_barrier();
    __builtin_amdgcn_sched_barrier(0);
    compute((NT - 2) % 3);
    // kt = NT-1
    asm volatile("s_waitcnt vmcnt(0)" ::: "memory");
    __builtin_amdgcn_sched_barrier(0);
    __builtin_amdgcn_s_barrier();
    __builtin_amdgcn_sched_barrier(0);
    compute((NT - 1) % 3);

    // epilogue: C/D map col=lane&15, row=(lane>>4)*4+reg
    const int crow0 = (lane >> 4) * 4;
    const int ccol = lane & 15;
    const long rowb = m0 + w * 16 + crow0;
#pragma unroll
    for (int j = 0; j < 8; ++j) {
        const int col = nt * 128 + j * 16 + ccol;
        const float b = bias[col];
#pragma unroll
        for (int q = 0; q < 4; ++q) {
            const long rgl = rowb + q;
            if (rgl < N) C[rgl * 256 + col] = fast_tanh(acc[j][q] + b);
        }
    }
}

// ---------------------------------------------------------------------------
extern "C" void kernel_launch(void* const* d_in, const int* in_sizes, int n_in,
                              void* d_out, int out_size, void* d_ws, size_t ws_size,
                              hipStream_t stream) {
    const float* x           = (const float*)d_in[0];
    const int*   edges       = (const int*)d_in[1];   // [4][2][400000] int32
    const float* weight      = (const float*)d_in[2]; // [4][256][256]
    const float* loop_weight = (const float*)d_in[3]; // [256][256]
    const float* h_bias      = (const float*)d_in[4]; // [256]
    float*       out         = (float*)d_out;
    (void)in_sizes; (void)n_in; (void)out_size; (void)ws_size;

    size_t off = 0;
    auto carve = [&](size_t bytes) -> void* {
        void* p = (char*)d_ws + off;
        off = (off + bytes + 255) & ~(size_t)255;
        return p;
    };

    _Float16* A_t  = (_Float16*)carve((size_t)MTILES * 32 * 2048 * sizeof(_Float16)); // 102.5 MB
    _Float16* xh   = (_Float16*)carve((size_t)AROWS * D * sizeof(_Float16));          // 25.6 MB
    _Float16* WT_t = (_Float16*)carve((size_t)2 * 40 * 4096 * sizeof(_Float16));      // 640 KB
    int*      gcnt  = (int*)carve((size_t)NBKT * sizeof(int) + 256);  // +ovf_n in tail
    int*      ovf_n = gcnt + NBKT;
    int2*     ovf   = (int2*)carve((size_t)MAXOVF * sizeof(int2));
    // ws total ~128.8 MB (proven available).
    // bucket array (8 MB) aliases d_out: dead before gemm_final overwrites it.
    uint* buckets = (uint*)d_out;  // NBKT*BCAP*4 = 8.03 MB <= 51.2 MB

    // one memset covers gcnt and ovf_n (adjacent carve)
    hipMemsetAsync(gcnt, 0, (size_t)NBKT * sizeof(int) + 256, stream);

    // fused prep: partition + convert + wt_build in one dispatch
    prep_kernel<<<PREP_BLOCKS, 256, 0, stream>>>(x, edges, weight, loop_weight,
                                                 xh, WT_t, gcnt, buckets,
                                                 ovf_n, ovf);

    // LDS slot build + gather fused (32-node parts, XCD bucket-affinity)
    bucket_gather_kernel<<<NBKT * 8, 256, 0, stream>>>(buckets, gcnt, xh,
                                                       ovf, ovf_n, A_t);
    // out = tanh([A_t | xh] @ WT_t + bias)
    gemm_final_kernel<<<dim3(2, MTILES), 256, 0, stream>>>(A_t, xh, WT_t, h_bias, out);
}